// Round 14
// baseline (572.420 us; speedup 1.0000x reference)
//
#include <hip/hip_runtime.h>
#include <cstdint>

typedef __attribute__((ext_vector_type(8))) short short8;
typedef __attribute__((ext_vector_type(4))) float f32x4;

static __device__ __forceinline__ unsigned short f2bf(float f) {
  unsigned int u = __float_as_uint(f);
  unsigned int r = (u + 0x7FFFu + ((u >> 16) & 1u)) >> 16;   // RNE
  return (unsigned short)r;
}
static __device__ __forceinline__ unsigned int pack2bf(float a, float b) {
  return (unsigned int)f2bf(a) | ((unsigned int)f2bf(b) << 16);
}
static __device__ __forceinline__ float2 bf2f(unsigned int u) {
  return make_float2(__uint_as_float(u << 16), __uint_as_float(u & 0xFFFF0000u));
}
static __device__ __forceinline__ void acc8(float* a, uint4 h, uint4 r) {
  float2 f, g;
  f = bf2f(h.x); g = bf2f(r.x); a[0] += f.x - g.x; a[1] += f.y - g.y;
  f = bf2f(h.y); g = bf2f(r.y); a[2] += f.x - g.x; a[3] += f.y - g.y;
  f = bf2f(h.z); g = bf2f(r.z); a[4] += f.x - g.x; a[5] += f.y - g.y;
  f = bf2f(h.w); g = bf2f(r.w); a[6] += f.x - g.x; a[7] += f.y - g.y;
}

// r_full[401][128] fp32 + packed bf16 copy; blocks 0..7 also zero gHist[1024]
__global__ void k_rfull(const float* __restrict__ coeff, const float* __restrict__ bases,
                        const float* __restrict__ selfr, float* __restrict__ rfull,
                        unsigned int* __restrict__ rfb, int* __restrict__ gHist) {
  __shared__ float row_s[128];
  int row = blockIdx.x, c = threadIdx.x;
  if (row < 8) gHist[row * 128 + c] = 0;
  float v;
  if (row == 400) {
    v = selfr[c];
  } else {
    int rr = row < 200 ? row : row - 200;
    float s = 0.f;
#pragma unroll 10
    for (int b = 0; b < 50; ++b) s += coeff[rr * 50 + b] * bases[b * 128 + c];
    v = (row < 200) ? s : -s;
  }
  rfull[row * 128 + c] = v;
  row_s[c] = v;
  __syncthreads();
  if (c < 64) rfb[row * 64 + c] = pack2bf(row_s[2 * c], row_s[2 * c + 1]);
}

// out[r][c] = sum_k A[r][k]*B[k][c], K=128, N=128; optional packed bf16 copy
__global__ void k_rmm(const float* __restrict__ A, const float* __restrict__ B,
                      float* __restrict__ out, unsigned int* __restrict__ outb) {
  __shared__ float row_s[128];
  int r = blockIdx.x, c = threadIdx.x;
  float s = 0.f;
#pragma unroll 8
  for (int k = 0; k < 128; ++k) s += A[r * 128 + k] * B[k * 128 + c];
  out[r * 128 + c] = s;
  if (outb) {
    row_s[c] = s;
    __syncthreads();
    if (c < 64) outb[r * 64 + c] = pack2bf(row_s[2 * c], row_s[2 * c + 1]);
  }
}

// convert fp32 table -> packed bf16-pair table
__global__ void k_cvt(const float* __restrict__ src, unsigned int* __restrict__ dst, int nPairs) {
  int i = blockIdx.x * blockDim.x + threadIdx.x;
  if (i >= nPairs) return;
  float2 v = *(const float2*)&src[(size_t)i * 2];
  dst[i] = pack2bf(v.x, v.y);
}

// both weight tensors -> transposed bf16, one dispatch (grid 384 x 256)
__global__ void k_wconv2(const float* __restrict__ W1, const float* __restrict__ W2,
                         unsigned short* __restrict__ WT1, unsigned short* __restrict__ WT2) {
  int gid = blockIdx.x * 256 + threadIdx.x;
  const int half = 128 * 384;
  const float* W = (gid < half) ? W1 : W2;
  unsigned short* WT = (gid < half) ? WT1 : WT2;
  int idx = (gid < half) ? gid : gid - half;
  int n = idx & 127, k = idx >> 7;
  int kk = k >> 7, kr = k & 127;
  WT[(size_t)n * 384 + k] = f2bf(W[(size_t)kk * 16384 + kr * 128 + n]);
}

// ---- binned CSR build: key = dst*3+y, bin = key>>9 (512 keys/bin) ----
// P1a: coarse histogram
__global__ __launch_bounds__(256) void k_p1a(const int* __restrict__ ei, const int* __restrict__ y,
                                             int* __restrict__ gHist, int nE, int nBins) {
  __shared__ int h[1024];
  for (int i = threadIdx.x; i < nBins; i += 256) h[i] = 0;
  __syncthreads();
  int e = blockIdx.x * 256 + threadIdx.x;
  if (e < nE) {
    int key = ei[nE + e] * 3 + y[e];
    atomicAdd(&h[key >> 9], 1);
  }
  __syncthreads();
  for (int i = threadIdx.x; i < nBins; i += 256)
    if (h[i]) atomicAdd(&gHist[i], h[i]);
}

// P1b: scan bins (single block, 1024 thr); init cursors; offsets[nKeys]=nE
__global__ void k_p1b(const int* __restrict__ gHist, int* __restrict__ coarseStart,
                      int* __restrict__ gCursor, int* __restrict__ offsets,
                      int nBins, int nKeys, int nE) {
  __shared__ int s[1024];
  int tid = threadIdx.x;
  int v = (tid < nBins) ? gHist[tid] : 0;
  s[tid] = v;
  __syncthreads();
  for (int off = 1; off < 1024; off <<= 1) {
    int t = (tid >= off) ? s[tid - off] : 0;
    __syncthreads();
    s[tid] += t;
    __syncthreads();
  }
  if (tid < nBins) { int ex = s[tid] - v; coarseStart[tid] = ex; gCursor[tid] = ex; }
  if (tid == 0) { coarseStart[nBins] = nE; offsets[nKeys] = nE; }
}

// P1c: partition edges into coarse bin regions (block-contiguous runs)
__global__ __launch_bounds__(256) void k_p1c(const int* __restrict__ ei, const int* __restrict__ et,
                                             const int* __restrict__ y, int* __restrict__ gCursor,
                                             uint2* __restrict__ coarseBuf, int nE, int nBins) {
  __shared__ int cnt[1024];
  __shared__ int base[1024];
  for (int i = threadIdx.x; i < nBins; i += 256) cnt[i] = 0;
  __syncthreads();
  int e = blockIdx.x * 256 + threadIdx.x;
  int key = 0, bin = 0, r = 0;
  unsigned int pk = 0;
  bool valid = e < nE;
  if (valid) {
    key = ei[nE + e] * 3 + y[e];
    bin = key >> 9;
    pk = (unsigned int)ei[e] | ((unsigned int)et[e] << 20);
    r = atomicAdd(&cnt[bin], 1);
  }
  __syncthreads();
  for (int i = threadIdx.x; i < nBins; i += 256) {
    int c = cnt[i];
    base[i] = c ? atomicAdd(&gCursor[i], c) : 0;
  }
  __syncthreads();
  if (valid) coarseBuf[base[bin] + r] = make_uint2((unsigned int)key, pk);
}

// P2: per-bin fine sort (block = 512 thr): hist -> scan -> offsets + local scatter
__global__ __launch_bounds__(512) void k_p2(const uint2* __restrict__ coarseBuf,
                                            const int* __restrict__ coarseStart,
                                            int* __restrict__ offsets,
                                            unsigned int* __restrict__ bucket,
                                            int nKeys) {
  __shared__ int h[512];
  const int b = blockIdx.x;
  const int tid = threadIdx.x;
  const int s0 = coarseStart[b], e0 = coarseStart[b + 1];
  const int key0 = b << 9;
  const int nk = min(512, nKeys - key0);
  h[tid] = 0;
  __syncthreads();
  for (int j = s0 + tid; j < e0; j += 512)
    atomicAdd(&h[(int)coarseBuf[j].x - key0], 1);
  __syncthreads();
  int v = h[tid];
  __syncthreads();
  for (int off = 1; off < 512; off <<= 1) {   // inclusive scan
    int t = (tid >= off) ? h[tid - off] : 0;
    __syncthreads();
    h[tid] += t;
    __syncthreads();
  }
  int cur = s0 + h[tid] - v;                  // global exclusive offset
  if (tid < nk) offsets[key0 + tid] = cur;
  __syncthreads();
  h[tid] = cur;
  __syncthreads();
  for (int j = s0 + tid; j < e0; j += 512) {
    uint2 d = coarseBuf[j];
    int slot = atomicAdd(&h[(int)d.x - key0], 1);
    bucket[slot] = d.y;
  }
}

// gather-aggregate: 4 keys per wave (16 lanes/key), uint4 (16B) loads, 2-edge unroll.
// Block 0 also zeroes the 256-float sums/sumsq region (consumed by the following GEMM).
__global__ __launch_bounds__(256) void k_agg4(const unsigned int* __restrict__ xb,
                                              const int* __restrict__ ids,
                                              const unsigned int* __restrict__ rb,
                                              const int* __restrict__ offsets,
                                              const unsigned int* __restrict__ packed,
                                              unsigned short* __restrict__ T,
                                              float* __restrict__ statZero, int nKeys) {
  if (blockIdx.x == 0) statZero[threadIdx.x] = 0.f;   // sums+sumsq (256 floats)
  int wid = blockIdx.x * 4 + (threadIdx.x >> 6);
  int lane = threadIdx.x & 63;
  int quad = lane >> 4, l16 = lane & 15;
  int key = wid * 4 + quad;
  if (key >= nKeys) return;
  int dst = key / 3, k = key - dst * 3;
  int s = offsets[key], e = offsets[key + 1];
  float a0[8] = {}, a1[8] = {};
  int j = s;
  for (; j + 1 < e; j += 2) {
    unsigned int p0 = packed[j], p1 = packed[j + 1];
    int s0 = p0 & 0xFFFFF, t0 = p0 >> 20;
    int s1 = p1 & 0xFFFFF, t1 = p1 >> 20;
    if (ids) { s0 = ids[s0]; s1 = ids[s1]; }
    uint4 h0 = *(const uint4*)&xb[(size_t)s0 * 64 + l16 * 4];
    uint4 r0 = *(const uint4*)&rb[(size_t)t0 * 64 + l16 * 4];
    uint4 h1 = *(const uint4*)&xb[(size_t)s1 * 64 + l16 * 4];
    uint4 r1 = *(const uint4*)&rb[(size_t)t1 * 64 + l16 * 4];
    acc8(a0, h0, r0);
    acc8(a1, h1, r1);
  }
  if (j < e) {
    unsigned int p0 = packed[j];
    int s0 = p0 & 0xFFFFF, t0 = p0 >> 20;
    if (ids) s0 = ids[s0];
    uint4 h0 = *(const uint4*)&xb[(size_t)s0 * 64 + l16 * 4];
    uint4 r0 = *(const uint4*)&rb[(size_t)t0 * 64 + l16 * 4];
    acc8(a0, h0, r0);
  }
  uint4 o;
  o.x = pack2bf(a0[0] + a1[0], a0[1] + a1[1]);
  o.y = pack2bf(a0[2] + a1[2], a0[3] + a1[3]);
  o.z = pack2bf(a0[4] + a1[4], a0[5] + a1[5]);
  o.w = pack2bf(a0[6] + a1[6], a0[7] + a1[7]);
  *(uint4*)&T[(size_t)dst * 384 + k * 128 + l16 * 8] = o;
}

// C[M x 128](bf16) = A[M x 384](bf16) @ WT^T.  MFMA 16x16x32 bf16.
// BM=128, BN=128, BK=32. Register-double-buffered LDS, one barrier per K-step.
// Fused BN-stats epilogue from fp32 acc; bf16 C store.
__global__ __launch_bounds__(256) void k_gemm_mfma(const unsigned short* __restrict__ A,
                                                   const unsigned short* __restrict__ WT,
                                                   unsigned short* __restrict__ C,
                                                   float* __restrict__ sums,
                                                   float* __restrict__ sumsq, int M) {
  __shared__ unsigned short As[2][128][40];
  __shared__ unsigned short Bs[2][128][40];
  __shared__ float sSum[128], sSq[128];
  const int tid = threadIdx.x;
  const int m0 = blockIdx.x * 128;
  const int wave = tid >> 6, lane = tid & 63;
  const int wrow = wave >> 1, wcol = wave & 1;
  const int quad = lane >> 4, l16 = lane & 15;
  f32x4 acc[4][4] = {};

  const int rr0 = tid >> 2, kc0 = (tid & 3) * 8;
  const int rr1 = rr0 + 64;
  const int ma0 = m0 + rr0, ma1 = m0 + rr1;
  const float4 fz = make_float4(0.f, 0.f, 0.f, 0.f);

  float4 apf0, apf1, bpf0, bpf1;
  apf0 = (ma0 < M) ? *(const float4*)&A[(size_t)ma0 * 384 + kc0] : fz;
  apf1 = (ma1 < M) ? *(const float4*)&A[(size_t)ma1 * 384 + kc0] : fz;
  bpf0 = *(const float4*)&WT[(size_t)rr0 * 384 + kc0];
  bpf1 = *(const float4*)&WT[(size_t)rr1 * 384 + kc0];
  *(float4*)&As[0][rr0][kc0] = apf0;
  *(float4*)&As[0][rr1][kc0] = apf1;
  *(float4*)&Bs[0][rr0][kc0] = bpf0;
  *(float4*)&Bs[0][rr1][kc0] = bpf1;
  __syncthreads();

  for (int it = 0; it < 12; ++it) {
    const int cur = it & 1;
    const int nxt = cur ^ 1;
    const bool pf = (it < 11);
    if (pf) {
      int kb = (it + 1) * 32;
      apf0 = (ma0 < M) ? *(const float4*)&A[(size_t)ma0 * 384 + kb + kc0] : fz;
      apf1 = (ma1 < M) ? *(const float4*)&A[(size_t)ma1 * 384 + kb + kc0] : fz;
      bpf0 = *(const float4*)&WT[(size_t)rr0 * 384 + kb + kc0];
      bpf1 = *(const float4*)&WT[(size_t)rr1 * 384 + kb + kc0];
    }
    short8 a[4], b[4];
#pragma unroll
    for (int t = 0; t < 4; ++t) a[t] = *(const short8*)&As[cur][wrow * 64 + t * 16 + l16][quad * 8];
#pragma unroll
    for (int t = 0; t < 4; ++t) b[t] = *(const short8*)&Bs[cur][wcol * 64 + t * 16 + l16][quad * 8];
#pragma unroll
    for (int rt = 0; rt < 4; ++rt)
#pragma unroll
      for (int ct = 0; ct < 4; ++ct)
        acc[rt][ct] = __builtin_amdgcn_mfma_f32_16x16x32_bf16(a[rt], b[ct], acc[rt][ct], 0, 0, 0);
    if (pf) {
      *(float4*)&As[nxt][rr0][kc0] = apf0;
      *(float4*)&As[nxt][rr1][kc0] = apf1;
      *(float4*)&Bs[nxt][rr0][kc0] = bpf0;
      *(float4*)&Bs[nxt][rr1][kc0] = bpf1;
      __syncthreads();
    }
  }

  if (tid < 128) { sSum[tid] = 0.f; sSq[tid] = 0.f; }
  __syncthreads();
  float ps[4] = {}, pq[4] = {};
#pragma unroll
  for (int rt = 0; rt < 4; ++rt) {
#pragma unroll
    for (int reg = 0; reg < 4; ++reg) {
      int m = m0 + wrow * 64 + rt * 16 + quad * 4 + reg;
      if (m < M) {
#pragma unroll
        for (int ct = 0; ct < 4; ++ct) {
          float v = acc[rt][ct][reg];
          int col = wcol * 64 + ct * 16 + l16;
          C[(size_t)m * 128 + col] = f2bf(v);
          ps[ct] += v; pq[ct] += v * v;
        }
      }
    }
  }
#pragma unroll
  for (int ct = 0; ct < 4; ++ct) {
    int col = wcol * 64 + ct * 16 + l16;
    atomicAdd(&sSum[col], ps[ct]);
    atomicAdd(&sSq[col], pq[ct]);
  }
  __syncthreads();
  if (tid < 128) {
    atomicAdd(&sums[tid], sSum[tid]);
    atomicAdd(&sumsq[tid], sSq[tid]);
  }
}

// norm + tanh (finalize fused: per-block recompute of scale/bias from sums/sumsq)
__global__ void k_norm(const unsigned int* __restrict__ Cb,
                       const float* __restrict__ sums, const float* __restrict__ sumsq,
                       const float* __restrict__ gamma, const float* __restrict__ beta,
                       float invN, unsigned int* __restrict__ xb, int nPairs) {
  __shared__ float sc_s[128], bi_s[128];
  if (threadIdx.x < 128) {
    int c = threadIdx.x;
    float mean = sums[c] * invN;
    float var = fmaxf(sumsq[c] * invN - mean * mean, 0.f);
    float sc = rsqrtf(var + 1e-5f) * gamma[c];
    sc_s[c] = sc;
    bi_s[c] = beta[c] - mean * sc;
  }
  __syncthreads();
  int i = blockIdx.x * blockDim.x + threadIdx.x;
  if (i >= nPairs) return;
  int j = i & 63;
  float2 v = bf2f(Cb[i]);
  float a = tanhf(fmaf(v.x, sc_s[2 * j], bi_s[2 * j]));
  float b = tanhf(fmaf(v.y, sc_s[2 * j + 1], bi_s[2 * j + 1]));
  xb[i] = pack2bf(a, b);
}

// one wave per triple: sum_d |x[h]+r[rel]-x[t]|
__global__ void k_score(const unsigned int* __restrict__ xb, const float* __restrict__ r,
                        const int* __restrict__ triples, float* __restrict__ out, int nT) {
  int gid = blockIdx.x * blockDim.x + threadIdx.x;
  int t = gid >> 6;
  if (t >= nT) return;
  int lane = gid & 63;
  int h = triples[t * 3], rel = triples[t * 3 + 1], tl = triples[t * 3 + 2];
  float2 a = bf2f(xb[(size_t)h * 64 + lane]);
  float2 b = *(const float2*)&r[(size_t)rel * 128 + lane * 2];
  float2 cc = bf2f(xb[(size_t)tl * 64 + lane]);
  float s = fabsf(a.x + b.x - cc.x) + fabsf(a.y + b.y - cc.y);
#pragma unroll
  for (int off = 32; off > 0; off >>= 1) s += __shfl_down(s, off);
  if (lane == 0) out[t] = s;
}

extern "C" void kernel_launch(void* const* d_in, const int* in_sizes, int n_in,
                              void* d_out, int out_size, void* d_ws, size_t ws_size,
                              hipStream_t stream) {
  const float* ent   = (const float*)d_in[0];
  const float* bases = (const float*)d_in[1];
  const float* coeff = (const float*)d_in[2];
  const float* selfr = (const float*)d_in[3];
  const float* W1    = (const float*)d_in[4];
  const float* relw1 = (const float*)d_in[5];
  const float* g1    = (const float*)d_in[6];
  const float* b1    = (const float*)d_in[7];
  const float* W2    = (const float*)d_in[8];
  const float* relw2 = (const float*)d_in[9];
  const float* g2    = (const float*)d_in[10];
  const float* b2    = (const float*)d_in[11];
  const int* ent_ids = (const int*)d_in[12];
  const int* ei      = (const int*)d_in[13];
  const int* et      = (const int*)d_in[14];
  const int* yk      = (const int*)d_in[15];
  const int* triples = (const int*)d_in[16];

  const int M  = in_sizes[0] / 128;   // 100000
  const int nE = in_sizes[14];        // 800000
  const int nT = in_sizes[16] / 3;    // 4096
  const int nKeys = M * 3;
  const int nBins = (nKeys + 511) >> 9;   // 586 for M=100000 (<=1024 supported)

  // workspace layout (~145 MB)
  float* p = (float*)d_ws;
  float* rfull = p; p += 401 * 128;
  float* r1    = p; p += 401 * 128;
  float* r2    = p; p += 401 * 128;
  float* sums  = p; p += 128;
  float* sumsq = p; p += 128;
  unsigned short* Cb  = (unsigned short*)p;          // M*128 bf16 GEMM output
  unsigned int* entbf = (unsigned int*)Cb;           // alias: bf16 ent pre-GEMM
  unsigned int* xb    = (unsigned int*)(Cb + (size_t)M * 128);  // M*64 packed bf16
  unsigned int* rfb   = xb + (size_t)M * 64;         // 401*64
  unsigned int* r1b   = rfb + 401 * 64;              // 401*64
  unsigned short* T   = (unsigned short*)(r1b + 401 * 64);  // M*384 bf16
  unsigned short* WT1 = T + (size_t)M * 384;
  unsigned short* WT2 = WT1 + 128 * 384;
  uintptr_t ip = (uintptr_t)(WT2 + 128 * 384);
  ip = (ip + 7) & ~(uintptr_t)7;
  uint2* coarseBuf = (uint2*)ip;                     // nE uint2
  int* offsets     = (int*)(coarseBuf + nE);         // nKeys + 1
  unsigned int* bucket = (unsigned int*)(offsets + nKeys + 1);  // nE
  int* gHist       = (int*)(bucket + nE);            // 1024
  int* coarseStart = gHist + 1024;                   // nBins + 1
  int* gCursor     = coarseStart + 1025;             // nBins

  float* out = (float*)d_out;

  const int mfmaBlocks = (M + 127) / 128;
  const int nPairs = M * 64;
  const int pairBlocks = (nPairs + 255) / 256;
  const int edgeBlocks = (nE + 255) / 256;
  const int aggBlocks  = (nKeys + 15) / 16;   // 4 keys/wave, 4 waves/block

  // relation chain (+ fused bf16 copies + gHist zero) + weight conversion
  k_rfull<<<401, 128, 0, stream>>>(coeff, bases, selfr, rfull, rfb, gHist);
  k_rmm<<<401, 128, 0, stream>>>(rfull, relw1, r1, r1b);
  k_rmm<<<401, 128, 0, stream>>>(r1, relw2, r2, nullptr);
  k_cvt<<<pairBlocks, 256, 0, stream>>>(ent, entbf, nPairs);
  k_wconv2<<<384, 256, 0, stream>>>(W1, W2, WT1, WT2);

  // binned CSR build
  k_p1a<<<edgeBlocks, 256, 0, stream>>>(ei, yk, gHist, nE, nBins);
  k_p1b<<<1, 1024, 0, stream>>>(gHist, coarseStart, gCursor, offsets, nBins, nKeys, nE);
  k_p1c<<<edgeBlocks, 256, 0, stream>>>(ei, et, yk, gCursor, coarseBuf, nE, nBins);
  k_p2<<<nBins, 512, 0, stream>>>(coarseBuf, coarseStart, offsets, bucket, nKeys);

  // ---- layer 1 ----
  k_agg4<<<aggBlocks, 256, 0, stream>>>(entbf, ent_ids, rfb, offsets, bucket, T, sums, nKeys);
  k_gemm_mfma<<<mfmaBlocks, 256, 0, stream>>>(T, WT1, Cb, sums, sumsq, M);
  k_norm<<<pairBlocks, 256, 0, stream>>>((unsigned int*)Cb, sums, sumsq, g1, b1, 1.0f / M, xb, nPairs);

  // ---- layer 2 ----
  k_agg4<<<aggBlocks, 256, 0, stream>>>(xb, nullptr, r1b, offsets, bucket, T, sums, nKeys);
  k_gemm_mfma<<<mfmaBlocks, 256, 0, stream>>>(T, WT2, Cb, sums, sumsq, M);
  k_norm<<<pairBlocks, 256, 0, stream>>>((unsigned int*)Cb, sums, sumsq, g2, b2, 1.0f / M, xb, nPairs);

  // ---- scoring ----
  k_score<<<(nT * 64 + 255) / 256, 256, 0, stream>>>(xb, r2, triples, out, nT);
}

// Round 15
// 473.226 us; speedup vs baseline: 1.2096x; 1.2096x over previous
//
#include <hip/hip_runtime.h>
#include <cstdint>

typedef __attribute__((ext_vector_type(8))) short short8;
typedef __attribute__((ext_vector_type(4))) float f32x4;

static __device__ __forceinline__ unsigned short f2bf(float f) {
  unsigned int u = __float_as_uint(f);
  unsigned int r = (u + 0x7FFFu + ((u >> 16) & 1u)) >> 16;   // RNE
  return (unsigned short)r;
}
static __device__ __forceinline__ unsigned int pack2bf(float a, float b) {
  return (unsigned int)f2bf(a) | ((unsigned int)f2bf(b) << 16);
}
static __device__ __forceinline__ float2 bf2f(unsigned int u) {
  return make_float2(__uint_as_float(u << 16), __uint_as_float(u & 0xFFFF0000u));
}
static __device__ __forceinline__ void acc8(float* a, uint4 h, uint4 r) {
  float2 f, g;
  f = bf2f(h.x); g = bf2f(r.x); a[0] += f.x - g.x; a[1] += f.y - g.y;
  f = bf2f(h.y); g = bf2f(r.y); a[2] += f.x - g.x; a[3] += f.y - g.y;
  f = bf2f(h.z); g = bf2f(r.z); a[4] += f.x - g.x; a[5] += f.y - g.y;
  f = bf2f(h.w); g = bf2f(r.w); a[6] += f.x - g.x; a[7] += f.y - g.y;
}

// r_full[401][128] fp32 + packed bf16 copy
__global__ void k_rfull(const float* __restrict__ coeff, const float* __restrict__ bases,
                        const float* __restrict__ selfr, float* __restrict__ rfull,
                        unsigned int* __restrict__ rfb) {
  __shared__ float row_s[128];
  int row = blockIdx.x, c = threadIdx.x;
  float v;
  if (row == 400) {
    v = selfr[c];
  } else {
    int rr = row < 200 ? row : row - 200;
    float s = 0.f;
#pragma unroll 10
    for (int b = 0; b < 50; ++b) s += coeff[rr * 50 + b] * bases[b * 128 + c];
    v = (row < 200) ? s : -s;
  }
  rfull[row * 128 + c] = v;
  row_s[c] = v;
  __syncthreads();
  if (c < 64) rfb[row * 64 + c] = pack2bf(row_s[2 * c], row_s[2 * c + 1]);
}

// out[r][c] = sum_k A[r][k]*B[k][c], K=128, N=128; optional packed bf16 copy
__global__ void k_rmm(const float* __restrict__ A, const float* __restrict__ B,
                      float* __restrict__ out, unsigned int* __restrict__ outb) {
  __shared__ float row_s[128];
  int r = blockIdx.x, c = threadIdx.x;
  float s = 0.f;
#pragma unroll 8
  for (int k = 0; k < 128; ++k) s += A[r * 128 + k] * B[k * 128 + c];
  out[r * 128 + c] = s;
  if (outb) {
    row_s[c] = s;
    __syncthreads();
    if (c < 64) outb[r * 64 + c] = pack2bf(row_s[2 * c], row_s[2 * c + 1]);
  }
}

// convert fp32 table -> packed bf16-pair table
__global__ void k_cvt(const float* __restrict__ src, unsigned int* __restrict__ dst, int nPairs) {
  int i = blockIdx.x * blockDim.x + threadIdx.x;
  if (i >= nPairs) return;
  float2 v = *(const float2*)&src[(size_t)i * 2];
  dst[i] = pack2bf(v.x, v.y);
}

// both weight tensors -> transposed bf16, one dispatch
__global__ void k_wconv2(const float* __restrict__ W1, const float* __restrict__ W2,
                         unsigned short* __restrict__ WT1, unsigned short* __restrict__ WT2) {
  int gid = blockIdx.x * 256 + threadIdx.x;
  const int half = 128 * 384;
  const float* W = (gid < half) ? W1 : W2;
  unsigned short* WT = (gid < half) ? WT1 : WT2;
  int idx = (gid < half) ? gid : gid - half;
  int n = idx & 127, k = idx >> 7;
  int kk = k >> 7, kr = k & 127;
  WT[(size_t)n * 384 + k] = f2bf(W[(size_t)kk * 16384 + kr * 128 + n]);
}

// ---- CSR build, range-partitioned: grid (8, nChunk); block handles key range
// [r*rsz, (r+1)*rsz) only. Linear block id = x + 8y -> XCD ~= x = r, so each
// counts/cursor/bucket region is touched by ONE XCD (no cross-XCD line bounce).
// Correct regardless of actual XCD mapping (every (range,chunk) covered).
__global__ __launch_bounds__(256) void k_histR(const int* __restrict__ ei, const int* __restrict__ y,
                                               int* __restrict__ counts, int nE, int rsz) {
  int r = blockIdx.x;
  int e0 = blockIdx.y * 1024;
#pragma unroll
  for (int i = 0; i < 4; ++i) {
    int e = e0 + i * 256 + threadIdx.x;
    if (e < nE) {
      int key = ei[nE + e] * 3 + y[e];
      if (key / rsz == r) atomicAdd(&counts[key], 1);
    }
  }
}

__global__ void k_scan1(const int* __restrict__ counts, int* __restrict__ local,
                        int* __restrict__ blockSums, int n) {
  __shared__ int sdata[1024];
  int tid = threadIdx.x;
  int i = blockIdx.x * 1024 + tid;
  int v = (i < n) ? counts[i] : 0;
  sdata[tid] = v;
  __syncthreads();
  for (int off = 1; off < 1024; off <<= 1) {
    int t = (tid >= off) ? sdata[tid - off] : 0;
    __syncthreads();
    sdata[tid] += t;
    __syncthreads();
  }
  if (i < n) local[i] = sdata[tid] - v;
  if (tid == 1023) blockSums[blockIdx.x] = sdata[1023];
}

__global__ void k_scan2(const int* __restrict__ blockSums, int* __restrict__ carries,
                        int* __restrict__ offsets, int n, int nb) {
  __shared__ int sdata[1024];
  int tid = threadIdx.x;
  int v = (tid < nb) ? blockSums[tid] : 0;
  sdata[tid] = v;
  __syncthreads();
  for (int off = 1; off < 1024; off <<= 1) {
    int t = (tid >= off) ? sdata[tid - off] : 0;
    __syncthreads();
    sdata[tid] += t;
    __syncthreads();
  }
  if (tid < nb) carries[tid] = sdata[tid] - v;
  if (tid == 1023) offsets[n] = sdata[1023];
}

__global__ void k_scan3(const int* __restrict__ local, const int* __restrict__ carries,
                        int* __restrict__ offsets, int* __restrict__ cursor, int n) {
  int i = blockIdx.x * 1024 + threadIdx.x;
  if (i >= n) return;
  int v = local[i] + carries[blockIdx.x];
  offsets[i] = v;
  cursor[i] = v;
}

// range-partitioned fill (same dispatch geometry as k_histR)
__global__ __launch_bounds__(256) void k_fillR(const int* __restrict__ ei, const int* __restrict__ et,
                                               const int* __restrict__ y, int* __restrict__ cursor,
                                               unsigned int* __restrict__ bucket, int nE, int rsz) {
  int r = blockIdx.x;
  int e0 = blockIdx.y * 1024;
#pragma unroll
  for (int i = 0; i < 4; ++i) {
    int e = e0 + i * 256 + threadIdx.x;
    if (e < nE) {
      int key = ei[nE + e] * 3 + y[e];
      if (key / rsz == r) {
        int slot = atomicAdd(&cursor[key], 1);
        bucket[slot] = (unsigned int)ei[e] | ((unsigned int)et[e] << 20);
      }
    }
  }
}

// gather-aggregate: 4 keys per wave (16 lanes/key), uint4 (16B) loads, 2-edge unroll.
// Block 0 also zeroes the 256-float sums/sumsq region (consumed by the following GEMM).
__global__ __launch_bounds__(256) void k_agg4(const unsigned int* __restrict__ xb,
                                              const int* __restrict__ ids,
                                              const unsigned int* __restrict__ rb,
                                              const int* __restrict__ offsets,
                                              const unsigned int* __restrict__ packed,
                                              unsigned short* __restrict__ T,
                                              float* __restrict__ statZero, int nKeys) {
  if (blockIdx.x == 0) statZero[threadIdx.x] = 0.f;   // sums+sumsq (256 floats)
  int wid = blockIdx.x * 4 + (threadIdx.x >> 6);
  int lane = threadIdx.x & 63;
  int quad = lane >> 4, l16 = lane & 15;
  int key = wid * 4 + quad;
  if (key >= nKeys) return;
  int dst = key / 3, k = key - dst * 3;
  int s = offsets[key], e = offsets[key + 1];
  float a0[8] = {}, a1[8] = {};
  int j = s;
  for (; j + 1 < e; j += 2) {
    unsigned int p0 = packed[j], p1 = packed[j + 1];
    int s0 = p0 & 0xFFFFF, t0 = p0 >> 20;
    int s1 = p1 & 0xFFFFF, t1 = p1 >> 20;
    if (ids) { s0 = ids[s0]; s1 = ids[s1]; }
    uint4 h0 = *(const uint4*)&xb[(size_t)s0 * 64 + l16 * 4];
    uint4 r0 = *(const uint4*)&rb[(size_t)t0 * 64 + l16 * 4];
    uint4 h1 = *(const uint4*)&xb[(size_t)s1 * 64 + l16 * 4];
    uint4 r1 = *(const uint4*)&rb[(size_t)t1 * 64 + l16 * 4];
    acc8(a0, h0, r0);
    acc8(a1, h1, r1);
  }
  if (j < e) {
    unsigned int p0 = packed[j];
    int s0 = p0 & 0xFFFFF, t0 = p0 >> 20;
    if (ids) s0 = ids[s0];
    uint4 h0 = *(const uint4*)&xb[(size_t)s0 * 64 + l16 * 4];
    uint4 r0 = *(const uint4*)&rb[(size_t)t0 * 64 + l16 * 4];
    acc8(a0, h0, r0);
  }
  uint4 o;
  o.x = pack2bf(a0[0] + a1[0], a0[1] + a1[1]);
  o.y = pack2bf(a0[2] + a1[2], a0[3] + a1[3]);
  o.z = pack2bf(a0[4] + a1[4], a0[5] + a1[5]);
  o.w = pack2bf(a0[6] + a1[6], a0[7] + a1[7]);
  *(uint4*)&T[(size_t)dst * 384 + k * 128 + l16 * 8] = o;
}

// C[M x 128](bf16) = A[M x 384](bf16) @ WT^T.  MFMA 16x16x32 bf16.
// BM=128, BN=128, BK=32. Register-double-buffered LDS, one barrier per K-step.
// Fused BN-stats epilogue from fp32 acc; bf16 C store.
__global__ __launch_bounds__(256) void k_gemm_mfma(const unsigned short* __restrict__ A,
                                                   const unsigned short* __restrict__ WT,
                                                   unsigned short* __restrict__ C,
                                                   float* __restrict__ sums,
                                                   float* __restrict__ sumsq, int M) {
  __shared__ unsigned short As[2][128][40];
  __shared__ unsigned short Bs[2][128][40];
  __shared__ float sSum[128], sSq[128];
  const int tid = threadIdx.x;
  const int m0 = blockIdx.x * 128;
  const int wave = tid >> 6, lane = tid & 63;
  const int wrow = wave >> 1, wcol = wave & 1;
  const int quad = lane >> 4, l16 = lane & 15;
  f32x4 acc[4][4] = {};

  const int rr0 = tid >> 2, kc0 = (tid & 3) * 8;
  const int rr1 = rr0 + 64;
  const int ma0 = m0 + rr0, ma1 = m0 + rr1;
  const float4 fz = make_float4(0.f, 0.f, 0.f, 0.f);

  float4 apf0, apf1, bpf0, bpf1;
  apf0 = (ma0 < M) ? *(const float4*)&A[(size_t)ma0 * 384 + kc0] : fz;
  apf1 = (ma1 < M) ? *(const float4*)&A[(size_t)ma1 * 384 + kc0] : fz;
  bpf0 = *(const float4*)&WT[(size_t)rr0 * 384 + kc0];
  bpf1 = *(const float4*)&WT[(size_t)rr1 * 384 + kc0];
  *(float4*)&As[0][rr0][kc0] = apf0;
  *(float4*)&As[0][rr1][kc0] = apf1;
  *(float4*)&Bs[0][rr0][kc0] = bpf0;
  *(float4*)&Bs[0][rr1][kc0] = bpf1;
  __syncthreads();

  for (int it = 0; it < 12; ++it) {
    const int cur = it & 1;
    const int nxt = cur ^ 1;
    const bool pf = (it < 11);
    if (pf) {
      int kb = (it + 1) * 32;
      apf0 = (ma0 < M) ? *(const float4*)&A[(size_t)ma0 * 384 + kb + kc0] : fz;
      apf1 = (ma1 < M) ? *(const float4*)&A[(size_t)ma1 * 384 + kb + kc0] : fz;
      bpf0 = *(const float4*)&WT[(size_t)rr0 * 384 + kb + kc0];
      bpf1 = *(const float4*)&WT[(size_t)rr1 * 384 + kb + kc0];
    }
    short8 a[4], b[4];
#pragma unroll
    for (int t = 0; t < 4; ++t) a[t] = *(const short8*)&As[cur][wrow * 64 + t * 16 + l16][quad * 8];
#pragma unroll
    for (int t = 0; t < 4; ++t) b[t] = *(const short8*)&Bs[cur][wcol * 64 + t * 16 + l16][quad * 8];
#pragma unroll
    for (int rt = 0; rt < 4; ++rt)
#pragma unroll
      for (int ct = 0; ct < 4; ++ct)
        acc[rt][ct] = __builtin_amdgcn_mfma_f32_16x16x32_bf16(a[rt], b[ct], acc[rt][ct], 0, 0, 0);
    if (pf) {
      *(float4*)&As[nxt][rr0][kc0] = apf0;
      *(float4*)&As[nxt][rr1][kc0] = apf1;
      *(float4*)&Bs[nxt][rr0][kc0] = bpf0;
      *(float4*)&Bs[nxt][rr1][kc0] = bpf1;
      __syncthreads();
    }
  }

  if (tid < 128) { sSum[tid] = 0.f; sSq[tid] = 0.f; }
  __syncthreads();
  float ps[4] = {}, pq[4] = {};
#pragma unroll
  for (int rt = 0; rt < 4; ++rt) {
#pragma unroll
    for (int reg = 0; reg < 4; ++reg) {
      int m = m0 + wrow * 64 + rt * 16 + quad * 4 + reg;
      if (m < M) {
#pragma unroll
        for (int ct = 0; ct < 4; ++ct) {
          float v = acc[rt][ct][reg];
          int col = wcol * 64 + ct * 16 + l16;
          C[(size_t)m * 128 + col] = f2bf(v);
          ps[ct] += v; pq[ct] += v * v;
        }
      }
    }
  }
#pragma unroll
  for (int ct = 0; ct < 4; ++ct) {
    int col = wcol * 64 + ct * 16 + l16;
    atomicAdd(&sSum[col], ps[ct]);
    atomicAdd(&sSq[col], pq[ct]);
  }
  __syncthreads();
  if (tid < 128) {
    atomicAdd(&sums[tid], sSum[tid]);
    atomicAdd(&sumsq[tid], sSq[tid]);
  }
}

// norm + tanh (finalize fused: per-block recompute of scale/bias from sums/sumsq)
__global__ void k_norm(const unsigned int* __restrict__ Cb,
                       const float* __restrict__ sums, const float* __restrict__ sumsq,
                       const float* __restrict__ gamma, const float* __restrict__ beta,
                       float invN, unsigned int* __restrict__ xb, int nPairs) {
  __shared__ float sc_s[128], bi_s[128];
  if (threadIdx.x < 128) {
    int c = threadIdx.x;
    float mean = sums[c] * invN;
    float var = fmaxf(sumsq[c] * invN - mean * mean, 0.f);
    float sc = rsqrtf(var + 1e-5f) * gamma[c];
    sc_s[c] = sc;
    bi_s[c] = beta[c] - mean * sc;
  }
  __syncthreads();
  int i = blockIdx.x * blockDim.x + threadIdx.x;
  if (i >= nPairs) return;
  int j = i & 63;
  float2 v = bf2f(Cb[i]);
  float a = tanhf(fmaf(v.x, sc_s[2 * j], bi_s[2 * j]));
  float b = tanhf(fmaf(v.y, sc_s[2 * j + 1], bi_s[2 * j + 1]));
  xb[i] = pack2bf(a, b);
}

// one wave per triple: sum_d |x[h]+r[rel]-x[t]|
__global__ void k_score(const unsigned int* __restrict__ xb, const float* __restrict__ r,
                        const int* __restrict__ triples, float* __restrict__ out, int nT) {
  int gid = blockIdx.x * blockDim.x + threadIdx.x;
  int t = gid >> 6;
  if (t >= nT) return;
  int lane = gid & 63;
  int h = triples[t * 3], rel = triples[t * 3 + 1], tl = triples[t * 3 + 2];
  float2 a = bf2f(xb[(size_t)h * 64 + lane]);
  float2 b = *(const float2*)&r[(size_t)rel * 128 + lane * 2];
  float2 cc = bf2f(xb[(size_t)tl * 64 + lane]);
  float s = fabsf(a.x + b.x - cc.x) + fabsf(a.y + b.y - cc.y);
#pragma unroll
  for (int off = 32; off > 0; off >>= 1) s += __shfl_down(s, off);
  if (lane == 0) out[t] = s;
}

extern "C" void kernel_launch(void* const* d_in, const int* in_sizes, int n_in,
                              void* d_out, int out_size, void* d_ws, size_t ws_size,
                              hipStream_t stream) {
  const float* ent   = (const float*)d_in[0];
  const float* bases = (const float*)d_in[1];
  const float* coeff = (const float*)d_in[2];
  const float* selfr = (const float*)d_in[3];
  const float* W1    = (const float*)d_in[4];
  const float* relw1 = (const float*)d_in[5];
  const float* g1    = (const float*)d_in[6];
  const float* b1    = (const float*)d_in[7];
  const float* W2    = (const float*)d_in[8];
  const float* relw2 = (const float*)d_in[9];
  const float* g2    = (const float*)d_in[10];
  const float* b2    = (const float*)d_in[11];
  const int* ent_ids = (const int*)d_in[12];
  const int* ei      = (const int*)d_in[13];
  const int* et      = (const int*)d_in[14];
  const int* yk      = (const int*)d_in[15];
  const int* triples = (const int*)d_in[16];

  const int M  = in_sizes[0] / 128;   // 100000
  const int nE = in_sizes[14];        // 800000
  const int nT = in_sizes[16] / 3;    // 4096
  const int nKeys = M * 3;
  const int nScanBlocks = (nKeys + 1023) / 1024;
  const int rsz = (nKeys + 7) / 8;    // keys per XCD range

  // workspace layout (~150 MB)
  float* p = (float*)d_ws;
  float* rfull = p; p += 401 * 128;
  float* r1    = p; p += 401 * 128;
  float* r2    = p; p += 401 * 128;
  float* sums  = p; p += 128;
  float* sumsq = p; p += 128;
  unsigned short* Cb  = (unsigned short*)p;          // M*128 bf16 GEMM output
  unsigned int* entbf = (unsigned int*)Cb;           // alias: bf16 ent pre-GEMM
  unsigned int* xb    = (unsigned int*)(Cb + (size_t)M * 128);  // M*64 packed bf16
  unsigned int* rfb   = xb + (size_t)M * 64;         // 401*64
  unsigned int* r1b   = rfb + 401 * 64;              // 401*64
  unsigned short* T   = (unsigned short*)(r1b + 401 * 64);  // M*384 bf16
  unsigned short* WT1 = T + (size_t)M * 384;
  unsigned short* WT2 = WT1 + 128 * 384;
  int* counts  = (int*)(WT2 + 128 * 384);            // nKeys
  int* offsets = counts + nKeys;                     // nKeys + 1
  int* cursor  = offsets + nKeys + 1;                // nKeys
  int* slocal  = cursor + nKeys;                     // nKeys
  int* sblock  = slocal + nKeys;                     // nScanBlocks
  int* scarry  = sblock + nScanBlocks;               // nScanBlocks
  unsigned int* bucket = (unsigned int*)(scarry + nScanBlocks);  // nE

  float* out = (float*)d_out;

  const int mfmaBlocks = (M + 127) / 128;
  const int nPairs = M * 64;
  const int pairBlocks = (nPairs + 255) / 256;
  const int aggBlocks  = (nKeys + 15) / 16;   // 4 keys/wave, 4 waves/block
  const dim3 rangedGrid(8, (nE + 1023) / 1024);

  // relation chain (+ fused bf16 copies) + weight conversion
  k_rfull<<<401, 128, 0, stream>>>(coeff, bases, selfr, rfull, rfb);
  k_rmm<<<401, 128, 0, stream>>>(rfull, relw1, r1, r1b);
  k_rmm<<<401, 128, 0, stream>>>(r1, relw2, r2, nullptr);
  k_cvt<<<pairBlocks, 256, 0, stream>>>(ent, entbf, nPairs);
  k_wconv2<<<384, 256, 0, stream>>>(W1, W2, WT1, WT2);

  // CSR over (dst, class): range-partitioned hist/fill, hierarchical scan
  hipMemsetAsync(counts, 0, (size_t)nKeys * sizeof(int), stream);
  k_histR<<<rangedGrid, 256, 0, stream>>>(ei, yk, counts, nE, rsz);
  k_scan1<<<nScanBlocks, 1024, 0, stream>>>(counts, slocal, sblock, nKeys);
  k_scan2<<<1, 1024, 0, stream>>>(sblock, scarry, offsets, nKeys, nScanBlocks);
  k_scan3<<<nScanBlocks, 1024, 0, stream>>>(slocal, scarry, offsets, cursor, nKeys);
  k_fillR<<<rangedGrid, 256, 0, stream>>>(ei, et, yk, cursor, bucket, nE, rsz);

  // ---- layer 1 ----
  k_agg4<<<aggBlocks, 256, 0, stream>>>(entbf, ent_ids, rfb, offsets, bucket, T, sums, nKeys);
  k_gemm_mfma<<<mfmaBlocks, 256, 0, stream>>>(T, WT1, Cb, sums, sumsq, M);
  k_norm<<<pairBlocks, 256, 0, stream>>>((unsigned int*)Cb, sums, sumsq, g1, b1, 1.0f / M, xb, nPairs);

  // ---- layer 2 ----
  k_agg4<<<aggBlocks, 256, 0, stream>>>(xb, nullptr, r1b, offsets, bucket, T, sums, nKeys);
  k_gemm_mfma<<<mfmaBlocks, 256, 0, stream>>>(T, WT2, Cb, sums, sumsq, M);
  k_norm<<<pairBlocks, 256, 0, stream>>>((unsigned int*)Cb, sums, sumsq, g2, b2, 1.0f / M, xb, nPairs);

  // ---- scoring ----
  k_score<<<(nT * 64 + 255) / 256, 256, 0, stream>>>(xb, r2, triples, out, nT);
}